// Round 16
// baseline (220.614 us; speedup 1.0000x reference)
//
#include <hip/hip_runtime.h>
#include <stdint.h>

#define IN_F 4096
#define OUT_F 4096
#define M_ROWS 4096   // B*S
#define BM 256
#define BN 128
#define BK 32
#define ABUF_B (BM * BK * 2)       // 16 KiB
#define BBUF_B (BN * BK * 2)       // 8 KiB
#define BUF_B (ABUF_B + BBUF_B)    // 24 KiB per depth

typedef __attribute__((ext_vector_type(8))) short bf16x8;
typedef __attribute__((ext_vector_type(4))) float f32x4;
typedef __attribute__((ext_vector_type(4))) float f4;
typedef __attribute__((ext_vector_type(8))) unsigned short u16x8;

__device__ __forceinline__ unsigned short f32_to_bf16_rne(float f) {
    uint32_t u = __float_as_uint(f);
    u += 0x7FFFu + ((u >> 16) & 1u);
    return (unsigned short)(u >> 16);
}

// ---- merged prepass: x fp32->bf16 (blocks [0,8192)), W expand (blocks [8192,16384)) ----
__global__ __launch_bounds__(256) void prep_kernel(const float* __restrict__ x,
                                                   const float* __restrict__ wsrc,
                                                   unsigned short* __restrict__ xb,
                                                   unsigned short* __restrict__ wb) {
    int b = blockIdx.x;
    if (b < 8192) {
        size_t g = (size_t)b * 256 + threadIdx.x;   // one per 8 elems
        const f4* xp = (const f4*)x + g * 2;
        f4 a = xp[0], c = xp[1];
        u16x8 r;
        r[0] = f32_to_bf16_rne(a[0]); r[1] = f32_to_bf16_rne(a[1]);
        r[2] = f32_to_bf16_rne(a[2]); r[3] = f32_to_bf16_rne(a[3]);
        r[4] = f32_to_bf16_rne(c[0]); r[5] = f32_to_bf16_rne(c[1]);
        r[6] = f32_to_bf16_rne(c[2]); r[7] = f32_to_bf16_rne(c[3]);
        *((u16x8*)xb + g) = r;
    } else {
        size_t g = (size_t)(b - 8192) * 256 + threadIdx.x;
        int o  = (int)(g >> 9);
        int i0 = ((int)g & 511) << 3;
        int bs = (o >> 7) << 7;            // GEMM never reads i < 128-aligned block start
        if (i0 >= bs) {
            int off = o * IN_F - ((o * (o - 1)) >> 1);
            u16x8 r;
#pragma unroll
            for (int j = 0; j < 8; ++j) {
                int i = i0 + j;
                float v = (i >= o) ? wsrc[off + (i - o)] : 0.0f;
                r[j] = f32_to_bf16_rne(v);
            }
            *((u16x8*)wb + g) = r;
        }
    }
}

// ---- LDS layout (R5-verified pair-line XOR swizzle, conflict-free) ----
// row = 32 bf16 = 64B = 4 slots of 16B; two rows share a 128B line.
// byte(row, slot) = (row>>1)*128 + (((row&1)*4 + slot) ^ ((row>>1)&7)) * 16
__device__ __forceinline__ const bf16x8* lds_frag(const char* buf, int row, int khalf) {
    const int line = row >> 1;
    const int pos  = ((((row & 1) << 2) + khalf) ^ (line & 7));
    return (const bf16x8*)(buf + line * 128 + pos * 16);
}

// stage 16 rows (1 KiB) via one global_load_lds; dest linear, source pre-swizzled
__device__ __forceinline__ void stage16(const unsigned short* __restrict__ G,
                                        char* lds_dst, int gr0, int k0, int lane) {
    const int pos  = (lane & 7) ^ (lane >> 3);
    const int row  = ((lane >> 3) << 1) + (pos >> 2);
    const int slot = pos & 3;
    const unsigned short* src = G + (size_t)(gr0 + row) * IN_F + k0 + slot * 8;
    __builtin_amdgcn_global_load_lds(
        (const __attribute__((address_space(1))) void*)src,
        (__attribute__((address_space(3))) void*)lds_dst, 16, 0, 0);
}

// one K32-tile: A 256x32 (4 units/wave) + B 128x32 (2 units/wave) = 6 issues/thread
__device__ __forceinline__ void stage_tile(const unsigned short* __restrict__ A,
                                           const unsigned short* __restrict__ W,
                                           char* buf, int m_base, int n_base, int k0,
                                           int wid, int lane) {
    char* bufA = buf;
    char* bufB = buf + ABUF_B;
#pragma unroll
    for (int q = 0; q < 4; ++q) {
        const int r0 = q * 64 + wid * 16;
        stage16(A, bufA + r0 * 64, m_base + r0, k0, lane);
    }
#pragma unroll
    for (int q = 0; q < 2; ++q) {
        const int r0 = q * 64 + wid * 16;
        stage16(W, bufB + r0 * 64, n_base + r0, k0, lane);
    }
}

// ---- main GEMM: C[m][n] = sum_{k>=n_base} A[m][k]*W[n][k] + bias[n] ----
// 256x128 tile, 4 waves (2Mx2N, wave 128x64), BK=32, depth-2 LDS = 48 KB -> 3 blocks/CU.
// R15's proven skeleton (counted vmcnt, publish + WAR barriers, burst compute);
// the lever vs R15: 3-way inter-block TLP + 0.375 reads/MFMA economics.
__global__ __launch_bounds__(256, 3) void tri_gemm_kernel(const unsigned short* __restrict__ A,
                                                          const unsigned short* __restrict__ W,
                                                          const float* __restrict__ bias,
                                                          float* __restrict__ C) {
    __shared__ __align__(16) char smem[2 * BUF_B];   // 48 KiB double buffer

    const int u = blockIdx.x;
    const int tile_n = u >> 4;          // desc-K dispatch -> greedy LPT via refill
    const int tile_m = u & 15;
    const int m_base = tile_m * BM;
    const int n_base = tile_n * BN;
    const int nt = (IN_F - n_base) / BK;   // 128 - 4*tile_n, even, min 4

    const int tid  = threadIdx.x;
    const int wid  = tid >> 6;
    const int lane = tid & 63;
    const int wr = wid >> 1;            // 0..1 (128-row band)
    const int wc = wid & 1;             // 0..1 (64-col band)
    const int frow  = lane & 15;
    const int khalf = lane >> 4;        // 0..3 -> the 4 k-slots of a K32 row

    char* buf0 = smem;
    char* buf1 = smem + BUF_B;

    f32x4 acc[8][4];
#pragma unroll
    for (int i = 0; i < 8; ++i)
#pragma unroll
        for (int j = 0; j < 4; ++j) acc[i][j] = (f32x4){0.f, 0.f, 0.f, 0.f};

    // prologue: tiles 0,1 staged (6 loads each per thread -> 12 outstanding)
    stage_tile(A, W, buf0, m_base, n_base, n_base,      wid, lane);
    stage_tile(A, W, buf1, m_base, n_base, n_base + BK, wid, lane);

    for (int t = 0; t < nt; ++t) {
        // publish tile t; keep tile t+1's 6 loads in flight (never drain mid-loop)
        if (t + 1 < nt) { asm volatile("s_waitcnt vmcnt(6)" ::: "memory"); }
        else            { asm volatile("s_waitcnt vmcnt(0)" ::: "memory"); }
        __builtin_amdgcn_sched_barrier(0);
        __builtin_amdgcn_s_barrier();
        __builtin_amdgcn_sched_barrier(0);

        char* cur = (t & 1) ? buf1 : buf0;
        const char* bufA = cur;
        const char* bufB = cur + ABUF_B;

        bf16x8 bfv[4];
#pragma unroll
        for (int nj = 0; nj < 4; ++nj)
            bfv[nj] = *lds_frag(bufB, wc * 64 + nj * 16 + frow, khalf);
        __builtin_amdgcn_s_setprio(1);
#pragma unroll
        for (int mi = 0; mi < 8; ++mi) {
            bf16x8 af = *lds_frag(bufA, wr * 128 + mi * 16 + frow, khalf);
#pragma unroll
            for (int nj = 0; nj < 4; ++nj)
                acc[mi][nj] = __builtin_amdgcn_mfma_f32_16x16x32_bf16(af, bfv[nj], acc[mi][nj], 0, 0, 0);
        }
        __builtin_amdgcn_s_setprio(0);

        // WAR close: all waves' reads of this buffer retired before restaging it
        asm volatile("s_waitcnt lgkmcnt(0)" ::: "memory");
        __builtin_amdgcn_sched_barrier(0);
        __builtin_amdgcn_s_barrier();
        __builtin_amdgcn_sched_barrier(0);

        if (t + 2 < nt)
            stage_tile(A, W, cur, m_base, n_base, n_base + (t + 2) * BK, wid, lane);
    }

    // ---- epilogue: D layout col=lane&15, row=(lane>>4)*4+q ----
    const int col0 = n_base + wc * 64;
    const int row0 = m_base + wr * 128;
#pragma unroll
    for (int nj = 0; nj < 4; ++nj) {
        const int col = col0 + nj * 16 + frow;
        const float bv = bias[col];
#pragma unroll
        for (int mi = 0; mi < 8; ++mi) {
            const int rbase = row0 + mi * 16 + khalf * 4;
#pragma unroll
            for (int q = 0; q < 4; ++q) {
                C[(size_t)(rbase + q) * OUT_F + col] = acc[mi][nj][q] + bv;
            }
        }
    }
}

extern "C" void kernel_launch(void* const* d_in, const int* in_sizes, int n_in,
                              void* d_out, int out_size, void* d_ws, size_t ws_size,
                              hipStream_t stream) {
    const float* x    = (const float*)d_in[0];
    const float* w    = (const float*)d_in[1];
    const float* bias = (const float*)d_in[2];
    float* out = (float*)d_out;

    unsigned short* xb = (unsigned short*)d_ws;                  // 32 MiB bf16 x
    unsigned short* wb = xb + (size_t)M_ROWS * IN_F;             // 32 MiB bf16 dense W

    prep_kernel<<<16384, 256, 0, stream>>>(x, w, xb, wb);
    tri_gemm_kernel<<<512, 256, 0, stream>>>(xb, wb, bias, out);
}

// Round 17
// 122.080 us; speedup vs baseline: 1.8071x; 1.8071x over previous
//
#include <hip/hip_runtime.h>
#include <stdint.h>

#define IN_F 4096
#define OUT_F 4096
#define M_ROWS 4096   // B*S
#define BM 128
#define BN 128
#define BK 64
#define ABUF_B (BM * BK * 2)       // 16 KiB
#define BBUF_B (BN * BK * 2)       // 16 KiB

typedef __attribute__((ext_vector_type(8))) short bf16x8;
typedef __attribute__((ext_vector_type(4))) float f32x4;
typedef __attribute__((ext_vector_type(4))) float f4;
typedef __attribute__((ext_vector_type(8))) unsigned short u16x8;

__device__ __forceinline__ unsigned short f32_to_bf16_rne(float f) {
    uint32_t u = __float_as_uint(f);
    u += 0x7FFFu + ((u >> 16) & 1u);
    return (unsigned short)(u >> 16);
}

// ---- merged prepass: x fp32->bf16 (blocks [0,8192)), W expand (blocks [8192,16384)) ----
__global__ __launch_bounds__(256) void prep_kernel(const float* __restrict__ x,
                                                   const float* __restrict__ wsrc,
                                                   unsigned short* __restrict__ xb,
                                                   unsigned short* __restrict__ wb) {
    int b = blockIdx.x;
    if (b < 8192) {
        size_t g = (size_t)b * 256 + threadIdx.x;   // one per 8 elems
        const f4* xp = (const f4*)x + g * 2;
        f4 a = xp[0], c = xp[1];
        u16x8 r;
        r[0] = f32_to_bf16_rne(a[0]); r[1] = f32_to_bf16_rne(a[1]);
        r[2] = f32_to_bf16_rne(a[2]); r[3] = f32_to_bf16_rne(a[3]);
        r[4] = f32_to_bf16_rne(c[0]); r[5] = f32_to_bf16_rne(c[1]);
        r[6] = f32_to_bf16_rne(c[2]); r[7] = f32_to_bf16_rne(c[3]);
        *((u16x8*)xb + g) = r;
    } else {
        size_t g = (size_t)(b - 8192) * 256 + threadIdx.x;
        int o  = (int)(g >> 9);
        int i0 = ((int)g & 511) << 3;
        int bs = (o >> 7) << 7;            // GEMM never reads i < 128-aligned block start
        if (i0 >= bs) {
            int off = o * IN_F - ((o * (o - 1)) >> 1);
            u16x8 r;
#pragma unroll
            for (int j = 0; j < 8; ++j) {
                int i = i0 + j;
                float v = (i >= o) ? wsrc[off + (i - o)] : 0.0f;
                r[j] = f32_to_bf16_rne(v);
            }
            *((u16x8*)wb + g) = r;
        }
    }
}

// ---- A staging: 8-row x 128B unit via global_load_lds; dest linear, source pre-swizzled ----
// LDS row layout: [row][8 slots x 16B], byte(row,slot) = row*128 + (slot ^ (row&7))*16
__device__ __forceinline__ void stage16(const unsigned short* __restrict__ G,
                                        char* lds_dst, int gr0, int k0, int lane) {
    const int lrow  = lane >> 3;                 // 0..7
    const int gslot = (lane & 7) ^ lrow;         // pre-swizzled source slot
    const unsigned short* src = G + (size_t)(gr0 + lrow) * IN_F + k0 + gslot * 8;
    __builtin_amdgcn_global_load_lds(
        (const __attribute__((address_space(1))) void*)src,
        (__attribute__((address_space(3))) void*)lds_dst, 16, 0, 0);
}

__device__ __forceinline__ void stageA(const unsigned short* __restrict__ A,
                                       char* bufA, int m_base, int k0,
                                       int wid, int lane) {
#pragma unroll
    for (int q = 0; q < 4; ++q) {                // A: 32 rows per wave, 4 DMA ops/thread
        const int r0 = q * 32 + wid * 8;
        stage16(A, bufA + r0 * 128, m_base + r0, k0, lane);
    }
}

// ---- B reg-staging: same per-lane source addressing as stage16, held in VGPRs ----
__device__ __forceinline__ void loadB(const unsigned short* __restrict__ W,
                                      bf16x8 (&reg)[4], int n_base, int k0,
                                      int wid, int lane) {
    const int lrow  = lane >> 3;
    const int gslot = (lane & 7) ^ lrow;
#pragma unroll
    for (int q = 0; q < 4; ++q) {                // B: 32 rows per wave, 4 loads/thread
        const int row = q * 32 + wid * 8 + lrow;
        reg[q] = *(const bf16x8*)(W + (size_t)(n_base + row) * IN_F + k0 + gslot * 8);
    }
}

// ds_write to the SAME linear dest the DMA would use -> identical LDS layout
__device__ __forceinline__ void writeB(char* bufB, bf16x8 (&reg)[4], int wid, int lane) {
#pragma unroll
    for (int q = 0; q < 4; ++q) {
        const int r0 = q * 32 + wid * 8;
        *(bf16x8*)(bufB + r0 * 128 + lane * 16) = reg[q];   // lanes stride-16B: conflict-free
    }
}

__device__ __forceinline__ const bf16x8* lds_frag(const char* buf, int row, int slot) {
    return (const bf16x8*)(buf + row * 128 + ((slot ^ (row & 7)) * 16));
}

// ---- main GEMM: C[m][n] = sum_{k>=n_base} A[m][k]*W[n][k] + bias[n] ----
// R15-exact skeleton (128^2, 4 waves, depth-2, 2 blocks/CU, counted vmcnt, 2 barriers);
// single change: B staged via global_load->reg->ds_write (parallel ingest path to A's DMA).
__global__ __launch_bounds__(256, 2) void tri_gemm_kernel(const unsigned short* __restrict__ A,
                                                          const unsigned short* __restrict__ W,
                                                          const float* __restrict__ bias,
                                                          float* __restrict__ C) {
    __shared__ __align__(16) char smem[2 * ABUF_B + 2 * BBUF_B];   // 64 KiB

    const int u = blockIdx.x;
    const int tile_n = u >> 5;          // desc-K dispatch -> greedy LPT via refill
    const int tile_m = u & 31;
    const int m_base = tile_m * BM;
    const int n_base = tile_n * BN;
    const int nt = (IN_F - n_base) / BK;   // 64 - 2*tile_n, even, min 2

    const int tid  = threadIdx.x;
    const int wid  = tid >> 6;
    const int lane = tid & 63;
    const int wr = wid >> 1;            // 0..1 (64-row band)
    const int wc = wid & 1;             // 0..1 (64-col band)
    const int frow  = lane & 15;
    const int khalf = lane >> 4;

    char* a0 = smem;
    char* a1 = smem + ABUF_B;
    char* b0 = smem + 2 * ABUF_B;
    char* b1 = b0 + BBUF_B;

    f32x4 acc[4][4];
#pragma unroll
    for (int i = 0; i < 4; ++i)
#pragma unroll
        for (int j = 0; j < 4; ++j) acc[i][j] = (f32x4){0.f, 0.f, 0.f, 0.f};

    bf16x8 regE[4], regO[4];    // B-reg sets, static parity via x2 unroll

    // prologue: batches for tiles 0,1 -> 16 vmem ops outstanding per thread
    stageA(A, a0, m_base, n_base, wid, lane);
    loadB(W, regE, n_base, n_base, wid, lane);
    stageA(A, a1, m_base, n_base + BK, wid, lane);
    loadB(W, regO, n_base, n_base + BK, wid, lane);

    // iter t: vmcnt(8) drains batch(t)={A(t) DMA, B(t) regs}, batch(t+1)'s 8 stay in flight
    auto iter = [&](int t, bf16x8 (&reg)[4]) {
        char* acur = (t & 1) ? a1 : a0;
        char* bcur = (t & 1) ? b1 : b0;

        if (t + 1 < nt) { asm volatile("s_waitcnt vmcnt(8)" ::: "memory"); }
        else            { asm volatile("s_waitcnt vmcnt(0)" ::: "memory"); }
        __builtin_amdgcn_sched_barrier(0);
        writeB(bcur, reg, wid, lane);                        // B(t) regs -> LDS (other buffer
        asm volatile("s_waitcnt lgkmcnt(0)" ::: "memory");   //  parity than iter t-1 readers)
        __builtin_amdgcn_sched_barrier(0);
        __builtin_amdgcn_s_barrier();                        // publish A(t)+B(t)
        __builtin_amdgcn_sched_barrier(0);

        bf16x8 af[2][4], bfr[2][4];
#pragma unroll
        for (int kh = 0; kh < 2; ++kh) {
            const int slot = kh * 4 + khalf;
#pragma unroll
            for (int mi = 0; mi < 4; ++mi)
                af[kh][mi] = *lds_frag(acur, wr * 64 + mi * 16 + frow, slot);
#pragma unroll
            for (int nj = 0; nj < 4; ++nj)
                bfr[kh][nj] = *lds_frag(bcur, wc * 64 + nj * 16 + frow, slot);
        }
        __builtin_amdgcn_s_setprio(1);
#pragma unroll
        for (int kh = 0; kh < 2; ++kh)
#pragma unroll
            for (int mi = 0; mi < 4; ++mi)
#pragma unroll
                for (int nj = 0; nj < 4; ++nj)
                    acc[mi][nj] = __builtin_amdgcn_mfma_f32_16x16x32_bf16(af[kh][mi], bfr[kh][nj], acc[mi][nj], 0, 0, 0);
        __builtin_amdgcn_s_setprio(0);

        // WAR close: all waves' reads of this parity retired before restaging it
        asm volatile("s_waitcnt lgkmcnt(0)" ::: "memory");
        __builtin_amdgcn_sched_barrier(0);
        __builtin_amdgcn_s_barrier();
        __builtin_amdgcn_sched_barrier(0);

        if (t + 2 < nt) {
            stageA(A, acur, m_base, n_base + (t + 2) * BK, wid, lane);
            loadB(W, reg, n_base, n_base + (t + 2) * BK, wid, lane);  // refill freed regs
        }
    };

    for (int t = 0; t < nt; t += 2) {   // nt always even
        iter(t, regE);
        iter(t + 1, regO);
    }

    // ---- epilogue: D layout col=lane&15, row=(lane>>4)*4+q ----
    const int col0 = n_base + wc * 64;
    const int row0 = m_base + wr * 64;
#pragma unroll
    for (int nj = 0; nj < 4; ++nj) {
        const int col = col0 + nj * 16 + frow;
        const float bv = bias[col];
#pragma unroll
        for (int mi = 0; mi < 4; ++mi) {
            const int rbase = row0 + mi * 16 + khalf * 4;
#pragma unroll
            for (int q = 0; q < 4; ++q) {
                C[(size_t)(rbase + q) * OUT_F + col] = acc[mi][nj][q] + bv;
            }
        }
    }
}

extern "C" void kernel_launch(void* const* d_in, const int* in_sizes, int n_in,
                              void* d_out, int out_size, void* d_ws, size_t ws_size,
                              hipStream_t stream) {
    const float* x    = (const float*)d_in[0];
    const float* w    = (const float*)d_in[1];
    const float* bias = (const float*)d_in[2];
    float* out = (float*)d_out;

    unsigned short* xb = (unsigned short*)d_ws;                  // 32 MiB bf16 x
    unsigned short* wb = xb + (size_t)M_ROWS * IN_F;             // 32 MiB bf16 dense W

    prep_kernel<<<16384, 256, 0, stream>>>(x, w, xb, wb);
    tri_gemm_kernel<<<1024, 256, 0, stream>>>(xb, wb, bias, out);
}